// Round 8
// baseline (225.103 us; speedup 1.0000x reference)
//
#include <hip/hip_runtime.h>

typedef __attribute__((ext_vector_type(8))) short short8;
typedef __attribute__((ext_vector_type(4))) short short4v;
typedef __attribute__((ext_vector_type(4))) float float4v;

#define T_SEQ 2048
#define CDIM 1024
#define NHEAD 16
#define HDIM 64
#define LROW 40  // padded LDS row stride in shorts

__device__ __forceinline__ unsigned short f2bf(float f) {
    unsigned u = __builtin_bit_cast(unsigned, f);
    u += 0x7FFF + ((u >> 16) & 1);
    return (unsigned short)(u >> 16);
}

// ---------------- conversion kernels ----------------
__global__ __launch_bounds__(256) void convert_f32_bf16_vec(
    const float* __restrict__ in, unsigned short* __restrict__ out) {
    int i = blockIdx.x * 256 + threadIdx.x;
    float4 v = ((const float4*)in)[i];
    ushort4 o;
    o.x = f2bf(v.x); o.y = f2bf(v.y); o.z = f2bf(v.z); o.w = f2bf(v.w);
    ((ushort4*)out)[i] = o;
}

// in [K][N] fp32 -> out [N][K] bf16
__global__ __launch_bounds__(256) void transpose_f32_bf16(
    const float* __restrict__ in, unsigned short* __restrict__ out, int K, int N) {
    __shared__ float tile[32][33];
    int kb = blockIdx.x * 32, nb = blockIdx.y * 32;
    int tx = threadIdx.x & 31, ty = threadIdx.x >> 5;  // ty 0..7
    for (int r = 0; r < 4; r++)
        tile[ty + r * 8][tx] = in[(size_t)(kb + ty + r * 8) * N + nb + tx];
    __syncthreads();
    for (int r = 0; r < 4; r++)
        out[(size_t)(nb + ty + r * 8) * K + kb + tx] = f2bf(tile[tx][ty + r * 8]);
}

// ---------------- QKV GEMM: 128x128, BK=32, reg-prefetch pipeline ----------
__global__ __launch_bounds__(256) void gemm_qkv(
    const unsigned short* __restrict__ A, const unsigned short* __restrict__ Bt,
    unsigned short* __restrict__ dK, unsigned short* __restrict__ dQ,
    unsigned short* __restrict__ dV) {
    const int K = 1024;
    const int NITER = K / 32;
    __shared__ unsigned short sA[2][128 * LROW];
    __shared__ unsigned short sB[2][128 * LROW];
    int tid = threadIdx.x, wave = tid >> 6, lane = tid & 63;
    int quad = lane >> 4, l16 = lane & 15;
    int wm = wave >> 1, wn = wave & 1;
    int blockM = blockIdx.y * 128, blockN = blockIdx.x * 128;
    int rlane = lane >> 2, seg = lane & 3;
    bool swapAB = (blockN >= 2048);  // V part: produce C^T

    const unsigned short* gA = A + (size_t)blockM * K;
    const unsigned short* gB = Bt + (size_t)blockN * K;

    float4v acc[4][4] = {};
    uint4 ra[2], rb[2];

    int srow0 = wave * 32 + rlane, srow1 = srow0 + 16;
    int soff0 = srow0 * LROW + seg * 8, soff1 = srow1 * LROW + seg * 8;
    const unsigned short* pA0 = gA + (size_t)srow0 * K + seg * 8;
    const unsigned short* pA1 = gA + (size_t)srow1 * K + seg * 8;
    const unsigned short* pB0 = gB + (size_t)srow0 * K + seg * 8;
    const unsigned short* pB1 = gB + (size_t)srow1 * K + seg * 8;

    ra[0] = *(const uint4*)pA0; ra[1] = *(const uint4*)pA1;
    rb[0] = *(const uint4*)pB0; rb[1] = *(const uint4*)pB1;
    *(uint4*)(sA[0] + soff0) = ra[0];
    *(uint4*)(sA[0] + soff1) = ra[1];
    *(uint4*)(sB[0] + soff0) = rb[0];
    *(uint4*)(sB[0] + soff1) = rb[1];

    int aoff = (wm * 64 + l16) * LROW + quad * 8;
    int boff = (wn * 64 + l16) * LROW + quad * 8;

    for (int it = 0; it < NITER; it++) {
        int cur = it & 1;
        __syncthreads();
        if (it + 1 < NITER) {
            pA0 += 32; pA1 += 32; pB0 += 32; pB1 += 32;
            ra[0] = *(const uint4*)pA0; ra[1] = *(const uint4*)pA1;
            rb[0] = *(const uint4*)pB0; rb[1] = *(const uint4*)pB1;
        }
        const unsigned short* cA = sA[cur];
        const unsigned short* cB = sB[cur];
        short8 af[4], bf[4];
        for (int i = 0; i < 4; i++)
            af[i] = *(const short8*)(cA + aoff + i * 16 * LROW);
        for (int j = 0; j < 4; j++)
            bf[j] = *(const short8*)(cB + boff + j * 16 * LROW);
        if (!swapAB) {
            for (int i = 0; i < 4; i++)
                for (int j = 0; j < 4; j++)
                    acc[i][j] = __builtin_amdgcn_mfma_f32_16x16x32_bf16(
                        af[i], bf[j], acc[i][j], 0, 0, 0);
        } else {
            for (int i = 0; i < 4; i++)
                for (int j = 0; j < 4; j++)
                    acc[i][j] = __builtin_amdgcn_mfma_f32_16x16x32_bf16(
                        bf[j], af[i], acc[i][j], 0, 0, 0);
        }
        if (it + 1 < NITER) {
            int nxt = cur ^ 1;
            *(uint4*)(sA[nxt] + soff0) = ra[0];
            *(uint4*)(sA[nxt] + soff1) = ra[1];
            *(uint4*)(sB[nxt] + soff0) = rb[0];
            *(uint4*)(sB[nxt] + soff1) = rb[1];
        }
    }

    if (!swapAB) {
        const float QSCL = 0.18033688011112042f;  // 0.125 * log2(e)
        for (int i = 0; i < 4; i++)
            for (int j = 0; j < 4; j++)
                for (int r = 0; r < 4; r++) {
                    int m = blockM + wm * 64 + i * 16 + quad * 4 + r;
                    int n = blockN + wn * 64 + j * 16 + l16;
                    int part = n >> 10, c = n & 1023;
                    int h = c >> 6, d = c & 63;
                    int bb = m >> 11, t = m & 2047;
                    int bh = bb * NHEAD + h;
                    if (part == 0) {
                        dK[(((size_t)bh * T_SEQ + t) << 6) + d] = f2bf(acc[i][j][r]);
                    } else {
                        dQ[(((size_t)bh * T_SEQ + t) << 6) + d] =
                            f2bf(acc[i][j][r] * QSCL);
                    }
                }
    } else {
        for (int i = 0; i < 4; i++)
            for (int j = 0; j < 4; j++)
                for (int r = 0; r < 4; r++) {
                    int n = blockN + wn * 64 + j * 16 + quad * 4 + r;
                    int m = blockM + wm * 64 + i * 16 + l16;
                    int c = n & 1023;
                    int h = c >> 6, d = c & 63;
                    int bb = m >> 11, t = m & 2047;
                    int bh = bb * NHEAD + h;
                    dV[((size_t)bh * HDIM + d) * T_SEQ + t] = f2bf(acc[i][j][r]);
                }
    }
}

// ---------------- proj GEMM: 64x64 tile, reg-prefetch pipeline -------------
__global__ __launch_bounds__(256) void gemm_proj64(
    const unsigned short* __restrict__ A, const unsigned short* __restrict__ Bt,
    const float* __restrict__ bias, float* __restrict__ out) {
    const int K = 1024;
    const int NITER = K / 32;
    __shared__ unsigned short sA[2][64 * LROW];
    __shared__ unsigned short sB[2][64 * LROW];
    int tid = threadIdx.x, wave = tid >> 6, lane = tid & 63;
    int quad = lane >> 4, l16 = lane & 15;
    int wm = wave >> 1, wn = wave & 1;
    int blockM = blockIdx.y * 64, blockN = blockIdx.x * 64;
    int rlane = lane >> 2, seg = lane & 3;

    const unsigned short* gA = A + (size_t)blockM * K;
    const unsigned short* gB = Bt + (size_t)blockN * K;

    float4v acc[2][2] = {};
    uint4 r2[2];

    // chunk c = wave*2+i: c<4 -> A rows c*16.., else B rows (c-4)*16..
    int c0 = wave * 2, c1 = wave * 2 + 1;
    int isB0 = c0 >> 2, cc0 = c0 & 3, row0 = cc0 * 16 + rlane;
    int isB1 = c1 >> 2, cc1 = c1 & 3, row1 = cc1 * 16 + rlane;
    const unsigned short* p0 = (isB0 ? gB : gA) + (size_t)row0 * K + seg * 8;
    const unsigned short* p1 = (isB1 ? gB : gA) + (size_t)row1 * K + seg * 8;
    int so0 = row0 * LROW + seg * 8, so1 = row1 * LROW + seg * 8;

    r2[0] = *(const uint4*)p0;
    r2[1] = *(const uint4*)p1;
    *(uint4*)((isB0 ? sB[0] : sA[0]) + so0) = r2[0];
    *(uint4*)((isB1 ? sB[0] : sA[0]) + so1) = r2[1];

    int aoff = (wm * 32 + l16) * LROW + quad * 8;
    int boff = (wn * 32 + l16) * LROW + quad * 8;

    for (int it = 0; it < NITER; it++) {
        int cur = it & 1;
        __syncthreads();
        if (it + 1 < NITER) {
            p0 += 32; p1 += 32;
            r2[0] = *(const uint4*)p0;
            r2[1] = *(const uint4*)p1;
        }
        const unsigned short* cA = sA[cur];
        const unsigned short* cB = sB[cur];
        short8 af[2], bf[2];
        for (int i = 0; i < 2; i++)
            af[i] = *(const short8*)(cA + aoff + i * 16 * LROW);
        for (int j = 0; j < 2; j++)
            bf[j] = *(const short8*)(cB + boff + j * 16 * LROW);
        for (int i = 0; i < 2; i++)
            for (int j = 0; j < 2; j++)
                acc[i][j] = __builtin_amdgcn_mfma_f32_16x16x32_bf16(
                    af[i], bf[j], acc[i][j], 0, 0, 0);
        if (it + 1 < NITER) {
            int nxt = cur ^ 1;
            *(uint4*)((isB0 ? sB[nxt] : sA[nxt]) + so0) = r2[0];
            *(uint4*)((isB1 ? sB[nxt] : sA[nxt]) + so1) = r2[1];
        }
    }

    for (int i = 0; i < 2; i++)
        for (int j = 0; j < 2; j++)
            for (int r = 0; r < 4; r++) {
                int m = blockM + wm * 32 + i * 16 + quad * 4 + r;
                int n = blockN + wn * 32 + j * 16 + l16;
                out[(size_t)m * CDIM + n] = acc[i][j][r] + bias[n];
            }
}

// ---------------- flash attention v5: 128-row Q-tiles, 2 strips/wave ------
// S^T = K*Q^T (Q pre-scaled by 0.125*log2e), fixed-max softmax (exp2(s-16)).
// K/V fragments (kf, vf) are q-independent -> reused for both 16-q strips:
// halves LDS reads per q-row. One 128-row tile per block; grid (32 bh, 16 y),
// xt = (y<8) ? 15-y : y-8 so co-resident block pairs balance (36 k-tiles).
__global__ __launch_bounds__(256) void attn_fwd(
    const unsigned short* __restrict__ Qp, const unsigned short* __restrict__ Kp,
    const unsigned short* __restrict__ Vt, unsigned short* __restrict__ att) {
    __shared__ unsigned short sK[2][64 * 72];
    __shared__ unsigned short sV[2][64 * 72];
    int tid = threadIdx.x, wave = tid >> 6, lane = tid & 63;
    int quad = lane >> 4, l16 = lane & 15;
    int bh = blockIdx.x;
    int bb = bh >> 4, h = bh & 15;
    size_t baseQ = (size_t)bh * T_SEQ * HDIM;  // [t][d]
    size_t baseV = (size_t)bh * HDIM * T_SEQ;  // [d][t]
    int row4 = tid >> 2, seg = tid & 3;

    int y = blockIdx.y;
    int xt = (y < 8) ? (15 - y) : (y - 8);
    int qb = xt * 128;
    int nt = 2 * xt + 2;

    // two q-strips per wave
    int q0 = qb + wave * 32 + l16;
    const unsigned short* qr0 = Qp + baseQ + (size_t)q0 * HDIM;
    short8 qf[2][2];
    qf[0][0] = *(const short8*)(qr0 + quad * 8);
    qf[0][1] = *(const short8*)(qr0 + 32 + quad * 8);
    qf[1][0] = *(const short8*)(qr0 + 16 * HDIM + quad * 8);
    qf[1][1] = *(const short8*)(qr0 + 16 * HDIM + 32 + quad * 8);

    float4v o[2][4] = {};
    float lsum[2] = {0.f, 0.f};

    // preload tile 0 and stage
    uint4 ka, kb2, va, vb;
    {
        const unsigned short* gk = Kp + baseQ + (size_t)row4 * HDIM + seg * 16;
        const unsigned short* gv = Vt + baseV + (size_t)row4 * T_SEQ + seg * 16;
        ka = *(const uint4*)gk; kb2 = *(const uint4*)(gk + 8);
        va = *(const uint4*)gv; vb = *(const uint4*)(gv + 8);
    }
    *(uint4*)(sK[0] + row4 * 72 + seg * 16) = ka;
    *(uint4*)(sK[0] + row4 * 72 + seg * 16 + 8) = kb2;
    *(uint4*)(sV[0] + row4 * 72 + seg * 16) = va;
    *(uint4*)(sV[0] + row4 * 72 + seg * 16 + 8) = vb;

    for (int t = 0; t < nt; t++) {
        int cur = t & 1;
        __syncthreads();
        if (t + 1 < nt) {
            const unsigned short* gk =
                Kp + baseQ + (size_t)((t + 1) * 64 + row4) * HDIM + seg * 16;
            const unsigned short* gv =
                Vt + baseV + (size_t)row4 * T_SEQ + (t + 1) * 64 + seg * 16;
            ka = *(const uint4*)gk; kb2 = *(const uint4*)(gk + 8);
            va = *(const uint4*)gv; vb = *(const uint4*)(gv + 8);
        }
        // wave-uniform causal skip: this wave's max q is qb+wave*32+31
        if (t * 64 <= qb + wave * 32 + 31) {
            const unsigned short* cK = sK[cur];
            const unsigned short* cV = sV[cur];

            // S phase: kf reused for both strips (8 b128 serve 32 q-cols)
            short8 kf[4][2];
            for (int sub = 0; sub < 4; sub++) {
                kf[sub][0] = *(const short8*)(cK + (sub * 16 + l16) * 72 + quad * 8);
                kf[sub][1] =
                    *(const short8*)(cK + (sub * 16 + l16) * 72 + 32 + quad * 8);
            }
            float4v sc[2][4];
            for (int s2 = 0; s2 < 2; s2++)
                for (int sub = 0; sub < 4; sub++) {
                    float4v z = {};
                    z = __builtin_amdgcn_mfma_f32_16x16x32_bf16(
                        kf[sub][0], qf[s2][0], z, 0, 0, 0);
                    z = __builtin_amdgcn_mfma_f32_16x16x32_bf16(
                        kf[sub][1], qf[s2][1], z, 0, 0, 0);
                    sc[s2][sub] = z;
                }

            // fixed-max softmax per strip
            unsigned ub[2][16];
            for (int s2 = 0; s2 < 2; s2++) {
                int qrow = qb + wave * 32 + s2 * 16 + l16;
                bool need_mask = (t * 64 + 63) > (qb + wave * 32 + s2 * 16);
                for (int sub = 0; sub < 4; sub++)
                    for (int r = 0; r < 4; r++) {
                        float v = sc[s2][sub][r];
                        if (need_mask) {
                            int kg = t * 64 + sub * 16 + quad * 4 + r;
                            v = (kg <= qrow) ? v : -1e30f;
                        }
                        float e = exp2f(v - 16.0f);
                        unsigned u = __builtin_bit_cast(unsigned, e) & 0xffff0000u;
                        ub[s2][sub * 4 + r] = u;
                        lsum[s2] += __builtin_bit_cast(float, u);
                    }
            }

            // PV phase: vf reused for both strips (16 b64 serve 32 q-cols)
            for (int sub = 0; sub < 4; sub++) {
                unsigned lo0 = __builtin_amdgcn_perm(ub[0][sub * 4 + 1],
                                                     ub[0][sub * 4 + 0], 0x07060302u);
                unsigned hi0 = __builtin_amdgcn_perm(ub[0][sub * 4 + 3],
                                                     ub[0][sub * 4 + 2], 0x07060302u);
                unsigned lo1 = __builtin_amdgcn_perm(ub[1][sub * 4 + 1],
                                                     ub[1][sub * 4 + 0], 0x07060302u);
                unsigned hi1 = __builtin_amdgcn_perm(ub[1][sub * 4 + 3],
                                                     ub[1][sub * 4 + 2], 0x07060302u);
                uint2 pk0 = {lo0, hi0}, pk1 = {lo1, hi1};
                short4v pf0 = __builtin_bit_cast(short4v, pk0);
                short4v pf1 = __builtin_bit_cast(short4v, pk1);
                for (int dc = 0; dc < 4; dc++) {
                    short4v vf = *(const short4v*)(
                        cV + (dc * 16 + l16) * 72 + sub * 16 + quad * 4);
                    o[0][dc] = __builtin_amdgcn_mfma_f32_16x16x16bf16_1k(
                        vf, pf0, o[0][dc], 0, 0, 0);
                    o[1][dc] = __builtin_amdgcn_mfma_f32_16x16x16bf16_1k(
                        vf, pf1, o[1][dc], 0, 0, 0);
                }
            }
        }
        if (t + 1 < nt) {
            int nxt = cur ^ 1;
            *(uint4*)(sK[nxt] + row4 * 72 + seg * 16) = ka;
            *(uint4*)(sK[nxt] + row4 * 72 + seg * 16 + 8) = kb2;
            *(uint4*)(sV[nxt] + row4 * 72 + seg * 16) = va;
            *(uint4*)(sV[nxt] + row4 * 72 + seg * 16 + 8) = vb;
        }
    }

    // row-sum reductions, then transpose epilogue through LDS
    for (int s2 = 0; s2 < 2; s2++) {
        lsum[s2] += __shfl_xor(lsum[s2], 16);
        lsum[s2] += __shfl_xor(lsum[s2], 32);
    }
    float inv0 = 1.0f / lsum[0], inv1 = 1.0f / lsum[1];

    __syncthreads();
    unsigned short* ep = &sK[0][0];  // 128 rows x 72 stride = both buffers
    for (int s2 = 0; s2 < 2; s2++) {
        float inv = s2 ? inv1 : inv0;
        for (int dc = 0; dc < 4; dc++) {
            short4v ov;
            for (int r = 0; r < 4; r++) ov[r] = (short)f2bf(o[s2][dc][r] * inv);
            *(short4v*)(ep + (wave * 32 + s2 * 16 + l16) * 72 + dc * 16 + quad * 4) =
                ov;
        }
    }
    __syncthreads();
    int orow = tid >> 1, half = tid & 1;
    const unsigned short* src = ep + orow * 72 + half * 32;
    uint4 a0 = *(const uint4*)(src);
    uint4 a1 = *(const uint4*)(src + 8);
    uint4 a2 = *(const uint4*)(src + 16);
    uint4 a3 = *(const uint4*)(src + 24);
    unsigned short* dst =
        att + (size_t)(bb * T_SEQ + qb + orow) * CDIM + h * HDIM + half * 32;
    *(uint4*)dst = a0;
    *(uint4*)(dst + 8) = a1;
    *(uint4*)(dst + 16) = a2;
    *(uint4*)(dst + 24) = a3;
}

// ---------------- launch ----------------
extern "C" void kernel_launch(void* const* d_in, const int* in_sizes, int n_in,
                              void* d_out, int out_size, void* d_ws, size_t ws_size,
                              hipStream_t stream) {
    const float* x      = (const float*)d_in[0];   // [2,2048,1024]
    const float* W_attn = (const float*)d_in[1];   // [1024,3072]
    const float* W_proj = (const float*)d_in[2];   // [1024,1024]
    const float* b_proj = (const float*)d_in[3];   // [1024]
    float* out = (float*)d_out;                    // [2,2048,1024]

    unsigned short* xb   = (unsigned short*)d_ws;          // 4096*1024
    unsigned short* WaT  = xb  + 4096 * 1024;              // 3072*1024 (transposed)
    unsigned short* WpT  = WaT + 3072 * 1024;              // 1024*1024 (transposed)
    unsigned short* Karr = WpT + 1024 * 1024;              // [B,H,T,64]
    unsigned short* Qarr = Karr + 2 * 16 * 2048 * 64;      // [B,H,T,64] pre-scaled
    unsigned short* Varr = Qarr + 2 * 16 * 2048 * 64;      // [B,H,64,T] transposed
    unsigned short* attb = Varr + 2 * 16 * 2048 * 64;      // 4096*1024

    convert_f32_bf16_vec<<<4096, 256, 0, stream>>>(x, xb);
    transpose_f32_bf16<<<dim3(32, 96), 256, 0, stream>>>(W_attn, WaT, 1024, 3072);
    transpose_f32_bf16<<<dim3(32, 32), 256, 0, stream>>>(W_proj, WpT, 1024, 1024);
    gemm_qkv<<<dim3(24, 32), 256, 0, stream>>>(xb, WaT, Karr, Qarr, Varr);
    attn_fwd<<<dim3(32, 16), 256, 0, stream>>>(Qarr, Karr, Varr, attb);
    gemm_proj64<<<dim3(16, 64), 256, 0, stream>>>(attb, WpT, b_proj, out);
}

// Round 9
// 199.469 us; speedup vs baseline: 1.1285x; 1.1285x over previous
//
#include <hip/hip_runtime.h>

typedef __attribute__((ext_vector_type(8))) short short8;
typedef __attribute__((ext_vector_type(4))) short short4v;
typedef __attribute__((ext_vector_type(4))) float float4v;

#define T_SEQ 2048
#define CDIM 1024
#define NHEAD 16
#define HDIM 64
#define LROW 40  // qkv LDS row stride (shorts)
#define PROW 72  // proj LDS row stride (shorts), BK=64 + pad

__device__ __forceinline__ unsigned short f2bf(float f) {
    unsigned u = __builtin_bit_cast(unsigned, f);
    u += 0x7FFF + ((u >> 16) & 1);
    return (unsigned short)(u >> 16);
}

// ---------------- conversion kernels ----------------
__global__ __launch_bounds__(256) void convert_f32_bf16_vec(
    const float* __restrict__ in, unsigned short* __restrict__ out) {
    int i = blockIdx.x * 256 + threadIdx.x;
    float4 v = ((const float4*)in)[i];
    ushort4 o;
    o.x = f2bf(v.x); o.y = f2bf(v.y); o.z = f2bf(v.z); o.w = f2bf(v.w);
    ((ushort4*)out)[i] = o;
}

// in [K][N] fp32 -> out [N][K] bf16
__global__ __launch_bounds__(256) void transpose_f32_bf16(
    const float* __restrict__ in, unsigned short* __restrict__ out, int K, int N) {
    __shared__ float tile[32][33];
    int kb = blockIdx.x * 32, nb = blockIdx.y * 32;
    int tx = threadIdx.x & 31, ty = threadIdx.x >> 5;  // ty 0..7
    for (int r = 0; r < 4; r++)
        tile[ty + r * 8][tx] = in[(size_t)(kb + ty + r * 8) * N + nb + tx];
    __syncthreads();
    for (int r = 0; r < 4; r++)
        out[(size_t)(nb + ty + r * 8) * K + kb + tx] = f2bf(tile[tx][ty + r * 8]);
}

// ---------------- QKV GEMM: 128x128, BK=32, reg-prefetch pipeline ----------
__global__ __launch_bounds__(256) void gemm_qkv(
    const unsigned short* __restrict__ A, const unsigned short* __restrict__ Bt,
    unsigned short* __restrict__ dK, unsigned short* __restrict__ dQ,
    unsigned short* __restrict__ dV) {
    const int K = 1024;
    const int NITER = K / 32;
    __shared__ unsigned short sA[2][128 * LROW];
    __shared__ unsigned short sB[2][128 * LROW];
    int tid = threadIdx.x, wave = tid >> 6, lane = tid & 63;
    int quad = lane >> 4, l16 = lane & 15;
    int wm = wave >> 1, wn = wave & 1;
    int blockM = blockIdx.y * 128, blockN = blockIdx.x * 128;
    int rlane = lane >> 2, seg = lane & 3;
    bool swapAB = (blockN >= 2048);  // V part: produce C^T

    const unsigned short* gA = A + (size_t)blockM * K;
    const unsigned short* gB = Bt + (size_t)blockN * K;

    float4v acc[4][4] = {};
    uint4 ra[2], rb[2];

    int srow0 = wave * 32 + rlane, srow1 = srow0 + 16;
    int soff0 = srow0 * LROW + seg * 8, soff1 = srow1 * LROW + seg * 8;
    const unsigned short* pA0 = gA + (size_t)srow0 * K + seg * 8;
    const unsigned short* pA1 = gA + (size_t)srow1 * K + seg * 8;
    const unsigned short* pB0 = gB + (size_t)srow0 * K + seg * 8;
    const unsigned short* pB1 = gB + (size_t)srow1 * K + seg * 8;

    ra[0] = *(const uint4*)pA0; ra[1] = *(const uint4*)pA1;
    rb[0] = *(const uint4*)pB0; rb[1] = *(const uint4*)pB1;
    *(uint4*)(sA[0] + soff0) = ra[0];
    *(uint4*)(sA[0] + soff1) = ra[1];
    *(uint4*)(sB[0] + soff0) = rb[0];
    *(uint4*)(sB[0] + soff1) = rb[1];

    int aoff = (wm * 64 + l16) * LROW + quad * 8;
    int boff = (wn * 64 + l16) * LROW + quad * 8;

    for (int it = 0; it < NITER; it++) {
        int cur = it & 1;
        __syncthreads();
        if (it + 1 < NITER) {
            pA0 += 32; pA1 += 32; pB0 += 32; pB1 += 32;
            ra[0] = *(const uint4*)pA0; ra[1] = *(const uint4*)pA1;
            rb[0] = *(const uint4*)pB0; rb[1] = *(const uint4*)pB1;
        }
        const unsigned short* cA = sA[cur];
        const unsigned short* cB = sB[cur];
        short8 af[4], bf[4];
        for (int i = 0; i < 4; i++)
            af[i] = *(const short8*)(cA + aoff + i * 16 * LROW);
        for (int j = 0; j < 4; j++)
            bf[j] = *(const short8*)(cB + boff + j * 16 * LROW);
        if (!swapAB) {
            for (int i = 0; i < 4; i++)
                for (int j = 0; j < 4; j++)
                    acc[i][j] = __builtin_amdgcn_mfma_f32_16x16x32_bf16(
                        af[i], bf[j], acc[i][j], 0, 0, 0);
        } else {
            for (int i = 0; i < 4; i++)
                for (int j = 0; j < 4; j++)
                    acc[i][j] = __builtin_amdgcn_mfma_f32_16x16x32_bf16(
                        bf[j], af[i], acc[i][j], 0, 0, 0);
        }
        if (it + 1 < NITER) {
            int nxt = cur ^ 1;
            *(uint4*)(sA[nxt] + soff0) = ra[0];
            *(uint4*)(sA[nxt] + soff1) = ra[1];
            *(uint4*)(sB[nxt] + soff0) = rb[0];
            *(uint4*)(sB[nxt] + soff1) = rb[1];
        }
    }

    if (!swapAB) {
        const float QSCL = 0.18033688011112042f;  // 0.125 * log2(e)
        for (int i = 0; i < 4; i++)
            for (int j = 0; j < 4; j++)
                for (int r = 0; r < 4; r++) {
                    int m = blockM + wm * 64 + i * 16 + quad * 4 + r;
                    int n = blockN + wn * 64 + j * 16 + l16;
                    int part = n >> 10, c = n & 1023;
                    int h = c >> 6, d = c & 63;
                    int bb = m >> 11, t = m & 2047;
                    int bh = bb * NHEAD + h;
                    if (part == 0) {
                        dK[(((size_t)bh * T_SEQ + t) << 6) + d] = f2bf(acc[i][j][r]);
                    } else {
                        dQ[(((size_t)bh * T_SEQ + t) << 6) + d] =
                            f2bf(acc[i][j][r] * QSCL);
                    }
                }
    } else {
        for (int i = 0; i < 4; i++)
            for (int j = 0; j < 4; j++)
                for (int r = 0; r < 4; r++) {
                    int n = blockN + wn * 64 + j * 16 + quad * 4 + r;
                    int m = blockM + wm * 64 + i * 16 + l16;
                    int c = n & 1023;
                    int h = c >> 6, d = c & 63;
                    int bb = m >> 11, t = m & 2047;
                    int bh = bb * NHEAD + h;
                    dV[((size_t)bh * HDIM + d) * T_SEQ + t] = f2bf(acc[i][j][r]);
                }
    }
}

// ---------------- proj GEMM: 64x64 tile, BK=64, reg-prefetch --------------
// 16 iters, 16 MFMA/wave-iter; PROW=72 pad (2-way bank aliasing = free);
// staging tid->(row=tid>>3, seg=tid&7): 8 contiguous 128B rows per wave.
// Grid (16, 64) = 1024 blocks, 36 KB LDS -> 4 blocks/CU.
__global__ __launch_bounds__(256) void gemm_proj(
    const unsigned short* __restrict__ A, const unsigned short* __restrict__ Bt,
    const float* __restrict__ bias, float* __restrict__ out) {
    const int K = 1024;
    const int NITER = K / 64;
    __shared__ unsigned short sA[2][64 * PROW];
    __shared__ unsigned short sB[2][64 * PROW];
    int tid = threadIdx.x, wave = tid >> 6, lane = tid & 63;
    int quad = lane >> 4, l16 = lane & 15;
    int wm = wave >> 1, wn = wave & 1;
    int blockM = blockIdx.y * 64, blockN = blockIdx.x * 64;

    int srow = tid >> 3;      // 0..31
    int sseg = tid & 7;       // 0..7
    const unsigned short* pA0 = A + (size_t)(blockM + srow) * K + sseg * 8;
    const unsigned short* pA1 = pA0 + (size_t)32 * K;
    const unsigned short* pB0 = Bt + (size_t)(blockN + srow) * K + sseg * 8;
    const unsigned short* pB1 = pB0 + (size_t)32 * K;
    int so0 = srow * PROW + sseg * 8;
    int so1 = (srow + 32) * PROW + sseg * 8;

    float4v acc[2][2] = {};
    uint4 ra0, ra1, rb0, rb1;

    ra0 = *(const uint4*)pA0; ra1 = *(const uint4*)pA1;
    rb0 = *(const uint4*)pB0; rb1 = *(const uint4*)pB1;
    *(uint4*)(sA[0] + so0) = ra0;
    *(uint4*)(sA[0] + so1) = ra1;
    *(uint4*)(sB[0] + so0) = rb0;
    *(uint4*)(sB[0] + so1) = rb1;

    int aoff = (wm * 32 + l16) * PROW + quad * 8;
    int boff = (wn * 32 + l16) * PROW + quad * 8;

    for (int it = 0; it < NITER; it++) {
        int cur = it & 1;
        __syncthreads();
        if (it + 1 < NITER) {
            pA0 += 64; pA1 += 64; pB0 += 64; pB1 += 64;
            ra0 = *(const uint4*)pA0; ra1 = *(const uint4*)pA1;
            rb0 = *(const uint4*)pB0; rb1 = *(const uint4*)pB1;
        }
        const unsigned short* cA = sA[cur];
        const unsigned short* cB = sB[cur];
        short8 af[2][2], bf[2][2];
        for (int i = 0; i < 2; i++)
            for (int k = 0; k < 2; k++)
                af[i][k] = *(const short8*)(cA + aoff + i * 16 * PROW + k * 32);
        for (int j = 0; j < 2; j++)
            for (int k = 0; k < 2; k++)
                bf[j][k] = *(const short8*)(cB + boff + j * 16 * PROW + k * 32);
        for (int i = 0; i < 2; i++)
            for (int j = 0; j < 2; j++) {
                acc[i][j] = __builtin_amdgcn_mfma_f32_16x16x32_bf16(
                    af[i][0], bf[j][0], acc[i][j], 0, 0, 0);
                acc[i][j] = __builtin_amdgcn_mfma_f32_16x16x32_bf16(
                    af[i][1], bf[j][1], acc[i][j], 0, 0, 0);
            }
        if (it + 1 < NITER) {
            int nxt = cur ^ 1;
            *(uint4*)(sA[nxt] + so0) = ra0;
            *(uint4*)(sA[nxt] + so1) = ra1;
            *(uint4*)(sB[nxt] + so0) = rb0;
            *(uint4*)(sB[nxt] + so1) = rb1;
        }
    }

    for (int i = 0; i < 2; i++)
        for (int j = 0; j < 2; j++)
            for (int r = 0; r < 4; r++) {
                int m = blockM + wm * 32 + i * 16 + quad * 4 + r;
                int n = blockN + wn * 32 + j * 16 + l16;
                out[(size_t)m * CDIM + n] = acc[i][j][r] + bias[n];
            }
}

// ---------------- flash attention v4 (R7): fixed-max softmax ---------------
// S^T = K*Q^T (Q pre-scaled by 0.125*log2e). Fixed max 16 in log2 domain:
// p = exp2(s - 16); no online max / alpha / in-loop shuffles. Double-buffered
// K/V via registers. Grid (bh=32, qpair=16), paired passes (x, 31-x).
__global__ __launch_bounds__(256) void attn_fwd(
    const unsigned short* __restrict__ Qp, const unsigned short* __restrict__ Kp,
    const unsigned short* __restrict__ Vt, unsigned short* __restrict__ att) {
    __shared__ unsigned short sK[2][64 * 72];
    __shared__ unsigned short sV[2][64 * 72];
    int tid = threadIdx.x, wave = tid >> 6, lane = tid & 63;
    int quad = lane >> 4, l16 = lane & 15;
    int bh = blockIdx.x;
    int bb = bh >> 4, h = bh & 15;
    size_t baseQ = (size_t)bh * T_SEQ * HDIM;  // [t][d]
    size_t baseV = (size_t)bh * HDIM * T_SEQ;  // [d][t]
    const int NT = T_SEQ / 64;  // 32
    int row4 = tid >> 2, seg = tid & 3;

    for (int pass = 0; pass < 2; pass++) {
        int xt = (pass == 0) ? blockIdx.y : (NT - 1 - blockIdx.y);
        int qb = xt * 64;
        int qrow = qb + wave * 16 + l16;

        const unsigned short* qr = Qp + baseQ + (size_t)qrow * HDIM;
        short8 qf0 = *(const short8*)(qr + quad * 8);
        short8 qf1 = *(const short8*)(qr + 32 + quad * 8);

        float4v o[4] = {};
        float lsum = 0.f;
        int nt = xt + 1;

        uint4 ka, kb2, va, vb;
        {
            const unsigned short* gk = Kp + baseQ + (size_t)row4 * HDIM + seg * 16;
            const unsigned short* gv = Vt + baseV + (size_t)row4 * T_SEQ + seg * 16;
            ka = *(const uint4*)gk; kb2 = *(const uint4*)(gk + 8);
            va = *(const uint4*)gv; vb = *(const uint4*)(gv + 8);
        }
        __syncthreads();  // prior pass epilogue LDS reads done
        *(uint4*)(sK[0] + row4 * 72 + seg * 16) = ka;
        *(uint4*)(sK[0] + row4 * 72 + seg * 16 + 8) = kb2;
        *(uint4*)(sV[0] + row4 * 72 + seg * 16) = va;
        *(uint4*)(sV[0] + row4 * 72 + seg * 16 + 8) = vb;

        for (int t = 0; t < nt; t++) {
            int cur = t & 1;
            __syncthreads();
            if (t + 1 < nt) {
                const unsigned short* gk =
                    Kp + baseQ + (size_t)((t + 1) * 64 + row4) * HDIM + seg * 16;
                const unsigned short* gv =
                    Vt + baseV + (size_t)row4 * T_SEQ + (t + 1) * 64 + seg * 16;
                ka = *(const uint4*)gk; kb2 = *(const uint4*)(gk + 8);
                va = *(const uint4*)gv; vb = *(const uint4*)(gv + 8);
            }

            const unsigned short* cK = sK[cur];
            const unsigned short* cV = sV[cur];
            float4v s[4];
            for (int sub = 0; sub < 4; sub++) {
                short8 kf0 = *(const short8*)(cK + (sub * 16 + l16) * 72 + quad * 8);
                short8 kf1 =
                    *(const short8*)(cK + (sub * 16 + l16) * 72 + 32 + quad * 8);
                float4v z = {};
                z = __builtin_amdgcn_mfma_f32_16x16x32_bf16(kf0, qf0, z, 0, 0, 0);
                z = __builtin_amdgcn_mfma_f32_16x16x32_bf16(kf1, qf1, z, 0, 0, 0);
                s[sub] = z;
            }

            bool need_mask = (t * 64 + 63) > (qb + wave * 16);  // wave-uniform
            float p[16];
            for (int sub = 0; sub < 4; sub++)
                for (int r = 0; r < 4; r++) {
                    float v = s[sub][r];
                    if (need_mask) {
                        int kg = t * 64 + sub * 16 + quad * 4 + r;
                        v = (kg <= qrow) ? v : -1e30f;
                    }
                    p[sub * 4 + r] = v;
                }
            unsigned ub[16];
            for (int i = 0; i < 16; i++) {
                float e = exp2f(p[i] - 16.0f);
                unsigned u = __builtin_bit_cast(unsigned, e) & 0xffff0000u;
                ub[i] = u;
                lsum += __builtin_bit_cast(float, u);
            }

            for (int sub = 0; sub < 4; sub++) {
                unsigned lo = __builtin_amdgcn_perm(ub[sub * 4 + 1], ub[sub * 4 + 0],
                                                    0x07060302u);
                unsigned hi = __builtin_amdgcn_perm(ub[sub * 4 + 3], ub[sub * 4 + 2],
                                                    0x07060302u);
                uint2 packed = {lo, hi};
                short4v pf = __builtin_bit_cast(short4v, packed);
                for (int dc = 0; dc < 4; dc++) {
                    short4v vf = *(const short4v*)(
                        cV + (dc * 16 + l16) * 72 + sub * 16 + quad * 4);
                    o[dc] = __builtin_amdgcn_mfma_f32_16x16x16bf16_1k(
                        vf, pf, o[dc], 0, 0, 0);
                }
            }

            if (t + 1 < nt) {
                int nxt = cur ^ 1;
                *(uint4*)(sK[nxt] + row4 * 72 + seg * 16) = ka;
                *(uint4*)(sK[nxt] + row4 * 72 + seg * 16 + 8) = kb2;
                *(uint4*)(sV[nxt] + row4 * 72 + seg * 16) = va;
                *(uint4*)(sV[nxt] + row4 * 72 + seg * 16 + 8) = vb;
            }
        }

        lsum += __shfl_xor(lsum, 16);
        lsum += __shfl_xor(lsum, 32);
        float inv = 1.0f / lsum;

        __syncthreads();
        for (int dc = 0; dc < 4; dc++) {
            short4v ov;
            for (int r = 0; r < 4; r++) ov[r] = (short)f2bf(o[dc][r] * inv);
            *(short4v*)(sK[0] + wave * 1152 + l16 * 72 + dc * 16 + quad * 4) = ov;
        }
        __syncthreads();
        int orow = lane >> 2, oseg = lane & 3;
        uint4 a = *(const uint4*)(sK[0] + wave * 1152 + orow * 72 + oseg * 16);
        uint4 b = *(const uint4*)(sK[0] + wave * 1152 + orow * 72 + oseg * 16 + 8);
        unsigned short* dst = att +
            (size_t)(bb * T_SEQ + qb + wave * 16 + orow) * CDIM + h * HDIM +
            oseg * 16;
        *(uint4*)dst = a;
        *(uint4*)(dst + 8) = b;
    }
}

// ---------------- launch ----------------
extern "C" void kernel_launch(void* const* d_in, const int* in_sizes, int n_in,
                              void* d_out, int out_size, void* d_ws, size_t ws_size,
                              hipStream_t stream) {
    const float* x      = (const float*)d_in[0];   // [2,2048,1024]
    const float* W_attn = (const float*)d_in[1];   // [1024,3072]
    const float* W_proj = (const float*)d_in[2];   // [1024,1024]
    const float* b_proj = (const float*)d_in[3];   // [1024]
    float* out = (float*)d_out;                    // [2,2048,1024]

    unsigned short* xb   = (unsigned short*)d_ws;          // 4096*1024
    unsigned short* WaT  = xb  + 4096 * 1024;              // 3072*1024 (transposed)
    unsigned short* WpT  = WaT + 3072 * 1024;              // 1024*1024 (transposed)
    unsigned short* Karr = WpT + 1024 * 1024;              // [B,H,T,64]
    unsigned short* Qarr = Karr + 2 * 16 * 2048 * 64;      // [B,H,T,64] pre-scaled
    unsigned short* Varr = Qarr + 2 * 16 * 2048 * 64;      // [B,H,64,T] transposed
    unsigned short* attb = Varr + 2 * 16 * 2048 * 64;      // 4096*1024

    convert_f32_bf16_vec<<<4096, 256, 0, stream>>>(x, xb);
    transpose_f32_bf16<<<dim3(32, 96), 256, 0, stream>>>(W_attn, WaT, 1024, 3072);
    transpose_f32_bf16<<<dim3(32, 32), 256, 0, stream>>>(W_proj, WpT, 1024, 1024);
    gemm_qkv<<<dim3(24, 32), 256, 0, stream>>>(xb, WaT, Karr, Qarr, Varr);
    attn_fwd<<<dim3(32, 16), 256, 0, stream>>>(Qarr, Karr, Varr, attb);
    gemm_proj<<<dim3(16, 64), 256, 0, stream>>>(attb, WpT, b_proj, out);
}

// Round 10
// 199.180 us; speedup vs baseline: 1.1302x; 1.0015x over previous
//
#include <hip/hip_runtime.h>

typedef __attribute__((ext_vector_type(8))) short short8;
typedef __attribute__((ext_vector_type(4))) short short4v;
typedef __attribute__((ext_vector_type(4))) float float4v;

#define T_SEQ 2048
#define CDIM 1024
#define NHEAD 16
#define HDIM 64
#define LROW 40  // qkv LDS row stride (shorts)
#define PROW 72  // proj LDS row stride (shorts), BK=64 + pad

__device__ __forceinline__ unsigned short f2bf(float f) {
    unsigned u = __builtin_bit_cast(unsigned, f);
    u += 0x7FFF + ((u >> 16) & 1);
    return (unsigned short)(u >> 16);
}

// ---------------- conversion kernels ----------------
__global__ __launch_bounds__(256) void convert_f32_bf16_vec(
    const float* __restrict__ in, unsigned short* __restrict__ out) {
    int i = blockIdx.x * 256 + threadIdx.x;
    float4 v = ((const float4*)in)[i];
    ushort4 o;
    o.x = f2bf(v.x); o.y = f2bf(v.y); o.z = f2bf(v.z); o.w = f2bf(v.w);
    ((ushort4*)out)[i] = o;
}

// in [K][N] fp32 -> out [N][K] bf16
__global__ __launch_bounds__(256) void transpose_f32_bf16(
    const float* __restrict__ in, unsigned short* __restrict__ out, int K, int N) {
    __shared__ float tile[32][33];
    int kb = blockIdx.x * 32, nb = blockIdx.y * 32;
    int tx = threadIdx.x & 31, ty = threadIdx.x >> 5;  // ty 0..7
    for (int r = 0; r < 4; r++)
        tile[ty + r * 8][tx] = in[(size_t)(kb + ty + r * 8) * N + nb + tx];
    __syncthreads();
    for (int r = 0; r < 4; r++)
        out[(size_t)(nb + ty + r * 8) * K + kb + tx] = f2bf(tile[tx][ty + r * 8]);
}

// ---------------- QKV GEMM: 128x128, BK=32, reg-prefetch pipeline ----------
// NOTE: staging addresses computed from loop-uniform kb (NOT hoisted pointers)
// so the unrolled loop folds kb*2 into the global_load immediate offset.
// Hoisted+incremented pointers cost ~20% (R9 post-mortem).
__global__ __launch_bounds__(256) void gemm_qkv(
    const unsigned short* __restrict__ A, const unsigned short* __restrict__ Bt,
    unsigned short* __restrict__ dK, unsigned short* __restrict__ dQ,
    unsigned short* __restrict__ dV) {
    const int K = 1024;
    const int NITER = K / 32;
    __shared__ unsigned short sA[2][128 * LROW];
    __shared__ unsigned short sB[2][128 * LROW];
    int tid = threadIdx.x, wave = tid >> 6, lane = tid & 63;
    int quad = lane >> 4, l16 = lane & 15;
    int wm = wave >> 1, wn = wave & 1;
    int blockM = blockIdx.y * 128, blockN = blockIdx.x * 128;
    int rlane = lane >> 2, seg = lane & 3;
    bool swapAB = (blockN >= 2048);  // V part: produce C^T

    const unsigned short* gA = A + (size_t)blockM * K;
    const unsigned short* gB = Bt + (size_t)blockN * K;

    float4v acc[4][4] = {};
    uint4 ra[2], rb[2];

    // staging offsets: row = wave*32 + i*16 + rlane, slot = seg
    int srow[2], soff[2];
    for (int i = 0; i < 2; i++) {
        srow[i] = wave * 32 + i * 16 + rlane;
        soff[i] = srow[i] * LROW + seg * 8;
    }

    // preload iter 0 into regs, stage to buf 0
    for (int i = 0; i < 2; i++) {
        ra[i] = *(const uint4*)(gA + (size_t)srow[i] * K + seg * 8);
        rb[i] = *(const uint4*)(gB + (size_t)srow[i] * K + seg * 8);
    }
    for (int i = 0; i < 2; i++) {
        *(uint4*)(sA[0] + soff[i]) = ra[i];
        *(uint4*)(sB[0] + soff[i]) = rb[i];
    }

    int aoff = (wm * 64 + l16) * LROW + quad * 8;
    int boff = (wn * 64 + l16) * LROW + quad * 8;

    for (int it = 0; it < NITER; it++) {
        int cur = it & 1;
        __syncthreads();  // buf[cur] staged; prior reads of buf[cur] done
        if (it + 1 < NITER) {
            int kb = (it + 1) * 32;
            for (int i = 0; i < 2; i++) {
                ra[i] = *(const uint4*)(gA + (size_t)srow[i] * K + kb + seg * 8);
                rb[i] = *(const uint4*)(gB + (size_t)srow[i] * K + kb + seg * 8);
            }
        }
        const unsigned short* cA = sA[cur];
        const unsigned short* cB = sB[cur];
        short8 af[4], bf[4];
        for (int i = 0; i < 4; i++)
            af[i] = *(const short8*)(cA + aoff + i * 16 * LROW);
        for (int j = 0; j < 4; j++)
            bf[j] = *(const short8*)(cB + boff + j * 16 * LROW);
        if (!swapAB) {
            for (int i = 0; i < 4; i++)
                for (int j = 0; j < 4; j++)
                    acc[i][j] = __builtin_amdgcn_mfma_f32_16x16x32_bf16(
                        af[i], bf[j], acc[i][j], 0, 0, 0);
        } else {
            for (int i = 0; i < 4; i++)
                for (int j = 0; j < 4; j++)
                    acc[i][j] = __builtin_amdgcn_mfma_f32_16x16x32_bf16(
                        bf[j], af[i], acc[i][j], 0, 0, 0);
        }
        if (it + 1 < NITER) {
            int nxt = cur ^ 1;
            for (int i = 0; i < 2; i++) {
                *(uint4*)(sA[nxt] + soff[i]) = ra[i];
                *(uint4*)(sB[nxt] + soff[i]) = rb[i];
            }
        }
    }

    if (!swapAB) {
        const float QSCL = 0.18033688011112042f;  // 0.125 * log2(e)
        for (int i = 0; i < 4; i++)
            for (int j = 0; j < 4; j++)
                for (int r = 0; r < 4; r++) {
                    int m = blockM + wm * 64 + i * 16 + quad * 4 + r;
                    int n = blockN + wn * 64 + j * 16 + l16;
                    int part = n >> 10, c = n & 1023;
                    int h = c >> 6, d = c & 63;
                    int bb = m >> 11, t = m & 2047;
                    int bh = bb * NHEAD + h;
                    if (part == 0) {
                        dK[(((size_t)bh * T_SEQ + t) << 6) + d] = f2bf(acc[i][j][r]);
                    } else {
                        dQ[(((size_t)bh * T_SEQ + t) << 6) + d] =
                            f2bf(acc[i][j][r] * QSCL);
                    }
                }
    } else {
        for (int i = 0; i < 4; i++)
            for (int j = 0; j < 4; j++)
                for (int r = 0; r < 4; r++) {
                    int n = blockN + wn * 64 + j * 16 + quad * 4 + r;
                    int m = blockM + wm * 64 + i * 16 + l16;
                    int c = n & 1023;
                    int h = c >> 6, d = c & 63;
                    int bb = m >> 11, t = m & 2047;
                    int bh = bb * NHEAD + h;
                    dV[((size_t)bh * HDIM + d) * T_SEQ + t] = f2bf(acc[i][j][r]);
                }
    }
}

// ---------------- proj GEMM: 64x64 tile, BK=64, reg-prefetch --------------
// kb-indexed staging addresses (immediate-offset friendly); PROW=72 pad.
__global__ __launch_bounds__(256) void gemm_proj(
    const unsigned short* __restrict__ A, const unsigned short* __restrict__ Bt,
    const float* __restrict__ bias, float* __restrict__ out) {
    const int K = 1024;
    const int NITER = K / 64;
    __shared__ unsigned short sA[2][64 * PROW];
    __shared__ unsigned short sB[2][64 * PROW];
    int tid = threadIdx.x, wave = tid >> 6, lane = tid & 63;
    int quad = lane >> 4, l16 = lane & 15;
    int wm = wave >> 1, wn = wave & 1;
    int blockM = blockIdx.y * 64, blockN = blockIdx.x * 64;

    int srow = tid >> 3;      // 0..31
    int sseg = tid & 7;       // 0..7
    const unsigned short* gA0 = A + (size_t)(blockM + srow) * K + sseg * 8;
    const unsigned short* gA1 = gA0 + (size_t)32 * K;
    const unsigned short* gB0 = Bt + (size_t)(blockN + srow) * K + sseg * 8;
    const unsigned short* gB1 = gB0 + (size_t)32 * K;
    int so0 = srow * PROW + sseg * 8;
    int so1 = (srow + 32) * PROW + sseg * 8;

    float4v acc[2][2] = {};
    uint4 ra0, ra1, rb0, rb1;

    ra0 = *(const uint4*)gA0; ra1 = *(const uint4*)gA1;
    rb0 = *(const uint4*)gB0; rb1 = *(const uint4*)gB1;
    *(uint4*)(sA[0] + so0) = ra0;
    *(uint4*)(sA[0] + so1) = ra1;
    *(uint4*)(sB[0] + so0) = rb0;
    *(uint4*)(sB[0] + so1) = rb1;

    int aoff = (wm * 32 + l16) * PROW + quad * 8;
    int boff = (wn * 32 + l16) * PROW + quad * 8;

    for (int it = 0; it < NITER; it++) {
        int cur = it & 1;
        __syncthreads();
        if (it + 1 < NITER) {
            int kb = (it + 1) * 64;
            ra0 = *(const uint4*)(gA0 + kb); ra1 = *(const uint4*)(gA1 + kb);
            rb0 = *(const uint4*)(gB0 + kb); rb1 = *(const uint4*)(gB1 + kb);
        }
        const unsigned short* cA = sA[cur];
        const unsigned short* cB = sB[cur];
        short8 af[2][2], bf[2][2];
        for (int i = 0; i < 2; i++)
            for (int k = 0; k < 2; k++)
                af[i][k] = *(const short8*)(cA + aoff + i * 16 * PROW + k * 32);
        for (int j = 0; j < 2; j++)
            for (int k = 0; k < 2; k++)
                bf[j][k] = *(const short8*)(cB + boff + j * 16 * PROW + k * 32);
        for (int i = 0; i < 2; i++)
            for (int j = 0; j < 2; j++) {
                acc[i][j] = __builtin_amdgcn_mfma_f32_16x16x32_bf16(
                    af[i][0], bf[j][0], acc[i][j], 0, 0, 0);
                acc[i][j] = __builtin_amdgcn_mfma_f32_16x16x32_bf16(
                    af[i][1], bf[j][1], acc[i][j], 0, 0, 0);
            }
        if (it + 1 < NITER) {
            int nxt = cur ^ 1;
            *(uint4*)(sA[nxt] + so0) = ra0;
            *(uint4*)(sA[nxt] + so1) = ra1;
            *(uint4*)(sB[nxt] + so0) = rb0;
            *(uint4*)(sB[nxt] + so1) = rb1;
        }
    }

    for (int i = 0; i < 2; i++)
        for (int j = 0; j < 2; j++)
            for (int r = 0; r < 4; r++) {
                int m = blockM + wm * 32 + i * 16 + quad * 4 + r;
                int n = blockN + wn * 32 + j * 16 + l16;
                out[(size_t)m * CDIM + n] = acc[i][j][r] + bias[n];
            }
}

// ---------------- flash attention v4 (R7): fixed-max softmax ---------------
__global__ __launch_bounds__(256) void attn_fwd(
    const unsigned short* __restrict__ Qp, const unsigned short* __restrict__ Kp,
    const unsigned short* __restrict__ Vt, unsigned short* __restrict__ att) {
    __shared__ unsigned short sK[2][64 * 72];
    __shared__ unsigned short sV[2][64 * 72];
    int tid = threadIdx.x, wave = tid >> 6, lane = tid & 63;
    int quad = lane >> 4, l16 = lane & 15;
    int bh = blockIdx.x;
    int bb = bh >> 4, h = bh & 15;
    size_t baseQ = (size_t)bh * T_SEQ * HDIM;  // [t][d]
    size_t baseV = (size_t)bh * HDIM * T_SEQ;  // [d][t]
    const int NT = T_SEQ / 64;  // 32
    int row4 = tid >> 2, seg = tid & 3;

    for (int pass = 0; pass < 2; pass++) {
        int xt = (pass == 0) ? blockIdx.y : (NT - 1 - blockIdx.y);
        int qb = xt * 64;
        int qrow = qb + wave * 16 + l16;

        const unsigned short* qr = Qp + baseQ + (size_t)qrow * HDIM;
        short8 qf0 = *(const short8*)(qr + quad * 8);
        short8 qf1 = *(const short8*)(qr + 32 + quad * 8);

        float4v o[4] = {};
        float lsum = 0.f;
        int nt = xt + 1;

        uint4 ka, kb2, va, vb;
        {
            const unsigned short* gk = Kp + baseQ + (size_t)row4 * HDIM + seg * 16;
            const unsigned short* gv = Vt + baseV + (size_t)row4 * T_SEQ + seg * 16;
            ka = *(const uint4*)gk; kb2 = *(const uint4*)(gk + 8);
            va = *(const uint4*)gv; vb = *(const uint4*)(gv + 8);
        }
        __syncthreads();  // prior pass epilogue LDS reads done
        *(uint4*)(sK[0] + row4 * 72 + seg * 16) = ka;
        *(uint4*)(sK[0] + row4 * 72 + seg * 16 + 8) = kb2;
        *(uint4*)(sV[0] + row4 * 72 + seg * 16) = va;
        *(uint4*)(sV[0] + row4 * 72 + seg * 16 + 8) = vb;

        for (int t = 0; t < nt; t++) {
            int cur = t & 1;
            __syncthreads();
            if (t + 1 < nt) {
                const unsigned short* gk =
                    Kp + baseQ + (size_t)((t + 1) * 64 + row4) * HDIM + seg * 16;
                const unsigned short* gv =
                    Vt + baseV + (size_t)row4 * T_SEQ + (t + 1) * 64 + seg * 16;
                ka = *(const uint4*)gk; kb2 = *(const uint4*)(gk + 8);
                va = *(const uint4*)gv; vb = *(const uint4*)(gv + 8);
            }

            const unsigned short* cK = sK[cur];
            const unsigned short* cV = sV[cur];
            float4v s[4];
            for (int sub = 0; sub < 4; sub++) {
                short8 kf0 = *(const short8*)(cK + (sub * 16 + l16) * 72 + quad * 8);
                short8 kf1 =
                    *(const short8*)(cK + (sub * 16 + l16) * 72 + 32 + quad * 8);
                float4v z = {};
                z = __builtin_amdgcn_mfma_f32_16x16x32_bf16(kf0, qf0, z, 0, 0, 0);
                z = __builtin_amdgcn_mfma_f32_16x16x32_bf16(kf1, qf1, z, 0, 0, 0);
                s[sub] = z;
            }

            bool need_mask = (t * 64 + 63) > (qb + wave * 16);  // wave-uniform
            float p[16];
            for (int sub = 0; sub < 4; sub++)
                for (int r = 0; r < 4; r++) {
                    float v = s[sub][r];
                    if (need_mask) {
                        int kg = t * 64 + sub * 16 + quad * 4 + r;
                        v = (kg <= qrow) ? v : -1e30f;
                    }
                    p[sub * 4 + r] = v;
                }
            unsigned ub[16];
            for (int i = 0; i < 16; i++) {
                float e = exp2f(p[i] - 16.0f);
                unsigned u = __builtin_bit_cast(unsigned, e) & 0xffff0000u;
                ub[i] = u;
                lsum += __builtin_bit_cast(float, u);
            }

            for (int sub = 0; sub < 4; sub++) {
                unsigned lo = __builtin_amdgcn_perm(ub[sub * 4 + 1], ub[sub * 4 + 0],
                                                    0x07060302u);
                unsigned hi = __builtin_amdgcn_perm(ub[sub * 4 + 3], ub[sub * 4 + 2],
                                                    0x07060302u);
                uint2 packed = {lo, hi};
                short4v pf = __builtin_bit_cast(short4v, packed);
                for (int dc = 0; dc < 4; dc++) {
                    short4v vf = *(const short4v*)(
                        cV + (dc * 16 + l16) * 72 + sub * 16 + quad * 4);
                    o[dc] = __builtin_amdgcn_mfma_f32_16x16x16bf16_1k(
                        vf, pf, o[dc], 0, 0, 0);
                }
            }

            if (t + 1 < nt) {
                int nxt = cur ^ 1;
                *(uint4*)(sK[nxt] + row4 * 72 + seg * 16) = ka;
                *(uint4*)(sK[nxt] + row4 * 72 + seg * 16 + 8) = kb2;
                *(uint4*)(sV[nxt] + row4 * 72 + seg * 16) = va;
                *(uint4*)(sV[nxt] + row4 * 72 + seg * 16 + 8) = vb;
            }
        }

        lsum += __shfl_xor(lsum, 16);
        lsum += __shfl_xor(lsum, 32);
        float inv = 1.0f / lsum;

        __syncthreads();
        for (int dc = 0; dc < 4; dc++) {
            short4v ov;
            for (int r = 0; r < 4; r++) ov[r] = (short)f2bf(o[dc][r] * inv);
            *(short4v*)(sK[0] + wave * 1152 + l16 * 72 + dc * 16 + quad * 4) = ov;
        }
        __syncthreads();
        int orow = lane >> 2, oseg = lane & 3;
        uint4 a = *(const uint4*)(sK[0] + wave * 1152 + orow * 72 + oseg * 16);
        uint4 b = *(const uint4*)(sK[0] + wave * 1152 + orow * 72 + oseg * 16 + 8);
        unsigned short* dst = att +
            (size_t)(bb * T_SEQ + qb + wave * 16 + orow) * CDIM + h * HDIM +
            oseg * 16;
        *(uint4*)dst = a;
        *(uint4*)(dst + 8) = b;
    }
}

// ---------------- launch ----------------
extern "C" void kernel_launch(void* const* d_in, const int* in_sizes, int n_in,
                              void* d_out, int out_size, void* d_ws, size_t ws_size,
                              hipStream_t stream) {
    const float* x      = (const float*)d_in[0];   // [2,2048,1024]
    const float* W_attn = (const float*)d_in[1];   // [1024,3072]
    const float* W_proj = (const float*)d_in[2];   // [1024,1024]
    const float* b_proj = (const float*)d_in[3];   // [1024]
    float* out = (float*)d_out;                    // [2,2048,1024]

    unsigned short* xb   = (unsigned short*)d_ws;          // 4096*1024
    unsigned short* WaT  = xb  + 4096 * 1024;              // 3072*1024 (transposed)
    unsigned short* WpT  = WaT + 3072 * 1024;              // 1024*1024 (transposed)
    unsigned short* Karr = WpT + 1024 * 1024;              // [B,H,T,64]
    unsigned short* Qarr = Karr + 2 * 16 * 2048 * 64;      // [B,H,T,64] pre-scaled
    unsigned short* Varr = Qarr + 2 * 16 * 2048 * 64;      // [B,H,64,T] transposed
    unsigned short* attb = Varr + 2 * 16 * 2048 * 64;      // 4096*1024

    convert_f32_bf16_vec<<<4096, 256, 0, stream>>>(x, xb);
    transpose_f32_bf16<<<dim3(32, 96), 256, 0, stream>>>(W_attn, WaT, 1024, 3072);
    transpose_f32_bf16<<<dim3(32, 32), 256, 0, stream>>>(W_proj, WpT, 1024, 1024);
    gemm_qkv<<<dim3(24, 32), 256, 0, stream>>>(xb, WaT, Karr, Qarr, Varr);
    attn_fwd<<<dim3(32, 16), 256, 0, stream>>>(Qarr, Karr, Varr, attb);
    gemm_proj<<<dim3(16, 64), 256, 0, stream>>>(attb, WpT, b_proj, out);
}

// Round 11
// 197.878 us; speedup vs baseline: 1.1376x; 1.0066x over previous
//
#include <hip/hip_runtime.h>

typedef __attribute__((ext_vector_type(8))) short short8;
typedef __attribute__((ext_vector_type(4))) short short4v;
typedef __attribute__((ext_vector_type(4))) float float4v;

#define T_SEQ 2048
#define CDIM 1024
#define NHEAD 16
#define HDIM 64
#define LROW 40  // qkv LDS row stride (shorts)
#define PROW 72  // proj LDS row stride (shorts), BK=64 + pad

__device__ __forceinline__ unsigned short f2bf(float f) {
    unsigned u = __builtin_bit_cast(unsigned, f);
    u += 0x7FFF + ((u >> 16) & 1);
    return (unsigned short)(u >> 16);
}

// ---------------- conversion kernels ----------------
__global__ __launch_bounds__(256) void convert_f32_bf16_vec(
    const float* __restrict__ in, unsigned short* __restrict__ out) {
    int i = blockIdx.x * 256 + threadIdx.x;
    float4 v = ((const float4*)in)[i];
    ushort4 o;
    o.x = f2bf(v.x); o.y = f2bf(v.y); o.z = f2bf(v.z); o.w = f2bf(v.w);
    ((ushort4*)out)[i] = o;
}

// in [K][N] fp32 -> out [N][K] bf16
__global__ __launch_bounds__(256) void transpose_f32_bf16(
    const float* __restrict__ in, unsigned short* __restrict__ out, int K, int N) {
    __shared__ float tile[32][33];
    int kb = blockIdx.x * 32, nb = blockIdx.y * 32;
    int tx = threadIdx.x & 31, ty = threadIdx.x >> 5;  // ty 0..7
    for (int r = 0; r < 4; r++)
        tile[ty + r * 8][tx] = in[(size_t)(kb + ty + r * 8) * N + nb + tx];
    __syncthreads();
    for (int r = 0; r < 4; r++)
        out[(size_t)(nb + ty + r * 8) * K + kb + tx] = f2bf(tile[tx][ty + r * 8]);
}

// ---------------- QKV GEMM: 128x128, BK=32, reg-prefetch pipeline ----------
// NOTE: staging addresses computed from loop-uniform kb (NOT hoisted pointers)
// so the unrolled loop folds kb*2 into the global_load immediate offset.
// Hoisted+incremented pointers cost ~20% (R9 post-mortem).
__global__ __launch_bounds__(256) void gemm_qkv(
    const unsigned short* __restrict__ A, const unsigned short* __restrict__ Bt,
    unsigned short* __restrict__ dK, unsigned short* __restrict__ dQ,
    unsigned short* __restrict__ dV) {
    const int K = 1024;
    const int NITER = K / 32;
    __shared__ unsigned short sA[2][128 * LROW];
    __shared__ unsigned short sB[2][128 * LROW];
    int tid = threadIdx.x, wave = tid >> 6, lane = tid & 63;
    int quad = lane >> 4, l16 = lane & 15;
    int wm = wave >> 1, wn = wave & 1;
    int blockM = blockIdx.y * 128, blockN = blockIdx.x * 128;
    int rlane = lane >> 2, seg = lane & 3;
    bool swapAB = (blockN >= 2048);  // V part: produce C^T

    const unsigned short* gA = A + (size_t)blockM * K;
    const unsigned short* gB = Bt + (size_t)blockN * K;

    float4v acc[4][4] = {};
    uint4 ra[2], rb[2];

    // staging offsets: row = wave*32 + i*16 + rlane, slot = seg
    int srow[2], soff[2];
    for (int i = 0; i < 2; i++) {
        srow[i] = wave * 32 + i * 16 + rlane;
        soff[i] = srow[i] * LROW + seg * 8;
    }

    // preload iter 0 into regs, stage to buf 0
    for (int i = 0; i < 2; i++) {
        ra[i] = *(const uint4*)(gA + (size_t)srow[i] * K + seg * 8);
        rb[i] = *(const uint4*)(gB + (size_t)srow[i] * K + seg * 8);
    }
    for (int i = 0; i < 2; i++) {
        *(uint4*)(sA[0] + soff[i]) = ra[i];
        *(uint4*)(sB[0] + soff[i]) = rb[i];
    }

    int aoff = (wm * 64 + l16) * LROW + quad * 8;
    int boff = (wn * 64 + l16) * LROW + quad * 8;

    for (int it = 0; it < NITER; it++) {
        int cur = it & 1;
        __syncthreads();  // buf[cur] staged; prior reads of buf[cur] done
        if (it + 1 < NITER) {
            int kb = (it + 1) * 32;
            for (int i = 0; i < 2; i++) {
                ra[i] = *(const uint4*)(gA + (size_t)srow[i] * K + kb + seg * 8);
                rb[i] = *(const uint4*)(gB + (size_t)srow[i] * K + kb + seg * 8);
            }
        }
        const unsigned short* cA = sA[cur];
        const unsigned short* cB = sB[cur];
        short8 af[4], bf[4];
        for (int i = 0; i < 4; i++)
            af[i] = *(const short8*)(cA + aoff + i * 16 * LROW);
        for (int j = 0; j < 4; j++)
            bf[j] = *(const short8*)(cB + boff + j * 16 * LROW);
        if (!swapAB) {
            for (int i = 0; i < 4; i++)
                for (int j = 0; j < 4; j++)
                    acc[i][j] = __builtin_amdgcn_mfma_f32_16x16x32_bf16(
                        af[i], bf[j], acc[i][j], 0, 0, 0);
        } else {
            for (int i = 0; i < 4; i++)
                for (int j = 0; j < 4; j++)
                    acc[i][j] = __builtin_amdgcn_mfma_f32_16x16x32_bf16(
                        bf[j], af[i], acc[i][j], 0, 0, 0);
        }
        if (it + 1 < NITER) {
            int nxt = cur ^ 1;
            for (int i = 0; i < 2; i++) {
                *(uint4*)(sA[nxt] + soff[i]) = ra[i];
                *(uint4*)(sB[nxt] + soff[i]) = rb[i];
            }
        }
    }

    if (!swapAB) {
        const float QSCL = 0.18033688011112042f;  // 0.125 * log2(e)
        for (int i = 0; i < 4; i++)
            for (int j = 0; j < 4; j++)
                for (int r = 0; r < 4; r++) {
                    int m = blockM + wm * 64 + i * 16 + quad * 4 + r;
                    int n = blockN + wn * 64 + j * 16 + l16;
                    int part = n >> 10, c = n & 1023;
                    int h = c >> 6, d = c & 63;
                    int bb = m >> 11, t = m & 2047;
                    int bh = bb * NHEAD + h;
                    if (part == 0) {
                        dK[(((size_t)bh * T_SEQ + t) << 6) + d] = f2bf(acc[i][j][r]);
                    } else {
                        dQ[(((size_t)bh * T_SEQ + t) << 6) + d] =
                            f2bf(acc[i][j][r] * QSCL);
                    }
                }
    } else {
        for (int i = 0; i < 4; i++)
            for (int j = 0; j < 4; j++)
                for (int r = 0; r < 4; r++) {
                    int n = blockN + wn * 64 + j * 16 + quad * 4 + r;
                    int m = blockM + wm * 64 + i * 16 + l16;
                    int c = n & 1023;
                    int h = c >> 6, d = c & 63;
                    int bb = m >> 11, t = m & 2047;
                    int bh = bb * NHEAD + h;
                    dV[((size_t)bh * HDIM + d) * T_SEQ + t] = f2bf(acc[i][j][r]);
                }
    }
}

// ---------------- proj GEMM: 64x64 tile, BK=64, reg-prefetch --------------
// kb-indexed staging addresses (immediate-offset friendly); PROW=72 pad.
__global__ __launch_bounds__(256) void gemm_proj(
    const unsigned short* __restrict__ A, const unsigned short* __restrict__ Bt,
    const float* __restrict__ bias, float* __restrict__ out) {
    const int K = 1024;
    const int NITER = K / 64;
    __shared__ unsigned short sA[2][64 * PROW];
    __shared__ unsigned short sB[2][64 * PROW];
    int tid = threadIdx.x, wave = tid >> 6, lane = tid & 63;
    int quad = lane >> 4, l16 = lane & 15;
    int wm = wave >> 1, wn = wave & 1;
    int blockM = blockIdx.y * 64, blockN = blockIdx.x * 64;

    int srow = tid >> 3;      // 0..31
    int sseg = tid & 7;       // 0..7
    const unsigned short* gA0 = A + (size_t)(blockM + srow) * K + sseg * 8;
    const unsigned short* gA1 = gA0 + (size_t)32 * K;
    const unsigned short* gB0 = Bt + (size_t)(blockN + srow) * K + sseg * 8;
    const unsigned short* gB1 = gB0 + (size_t)32 * K;
    int so0 = srow * PROW + sseg * 8;
    int so1 = (srow + 32) * PROW + sseg * 8;

    float4v acc[2][2] = {};
    uint4 ra0, ra1, rb0, rb1;

    ra0 = *(const uint4*)gA0; ra1 = *(const uint4*)gA1;
    rb0 = *(const uint4*)gB0; rb1 = *(const uint4*)gB1;
    *(uint4*)(sA[0] + so0) = ra0;
    *(uint4*)(sA[0] + so1) = ra1;
    *(uint4*)(sB[0] + so0) = rb0;
    *(uint4*)(sB[0] + so1) = rb1;

    int aoff = (wm * 32 + l16) * PROW + quad * 8;
    int boff = (wn * 32 + l16) * PROW + quad * 8;

    for (int it = 0; it < NITER; it++) {
        int cur = it & 1;
        __syncthreads();
        if (it + 1 < NITER) {
            int kb = (it + 1) * 64;
            ra0 = *(const uint4*)(gA0 + kb); ra1 = *(const uint4*)(gA1 + kb);
            rb0 = *(const uint4*)(gB0 + kb); rb1 = *(const uint4*)(gB1 + kb);
        }
        const unsigned short* cA = sA[cur];
        const unsigned short* cB = sB[cur];
        short8 af[2][2], bf[2][2];
        for (int i = 0; i < 2; i++)
            for (int k = 0; k < 2; k++)
                af[i][k] = *(const short8*)(cA + aoff + i * 16 * PROW + k * 32);
        for (int j = 0; j < 2; j++)
            for (int k = 0; k < 2; k++)
                bf[j][k] = *(const short8*)(cB + boff + j * 16 * PROW + k * 32);
        for (int i = 0; i < 2; i++)
            for (int j = 0; j < 2; j++) {
                acc[i][j] = __builtin_amdgcn_mfma_f32_16x16x32_bf16(
                    af[i][0], bf[j][0], acc[i][j], 0, 0, 0);
                acc[i][j] = __builtin_amdgcn_mfma_f32_16x16x32_bf16(
                    af[i][1], bf[j][1], acc[i][j], 0, 0, 0);
            }
        if (it + 1 < NITER) {
            int nxt = cur ^ 1;
            *(uint4*)(sA[nxt] + so0) = ra0;
            *(uint4*)(sA[nxt] + so1) = ra1;
            *(uint4*)(sB[nxt] + so0) = rb0;
            *(uint4*)(sB[nxt] + so1) = rb1;
        }
    }

    for (int i = 0; i < 2; i++)
        for (int j = 0; j < 2; j++)
            for (int r = 0; r < 4; r++) {
                int m = blockM + wm * 32 + i * 16 + quad * 4 + r;
                int n = blockN + wn * 32 + j * 16 + l16;
                out[(size_t)m * CDIM + n] = acc[i][j][r] + bias[n];
            }
}

// ---------------- flash attention v6: one q-tile per block ----------------
// Same inner structure as R7/R10 (fixed-max softmax, reg-prefetch dbuf) but
// the 2-pass pairing is split into the grid: (32 bh, 32 xt) = 1024 blocks =
// 4 blocks/CU, 16 waves/CU -> cross-block phase overlap. xt = 31 - y so the
// longest blocks dispatch first. Same-bh blocks share XCD (id % 8 == bh % 8).
__global__ __launch_bounds__(256) void attn_fwd(
    const unsigned short* __restrict__ Qp, const unsigned short* __restrict__ Kp,
    const unsigned short* __restrict__ Vt, unsigned short* __restrict__ att) {
    __shared__ unsigned short sK[2][64 * 72];
    __shared__ unsigned short sV[2][64 * 72];
    int tid = threadIdx.x, wave = tid >> 6, lane = tid & 63;
    int quad = lane >> 4, l16 = lane & 15;
    int bh = blockIdx.x;
    int bb = bh >> 4, h = bh & 15;
    size_t baseQ = (size_t)bh * T_SEQ * HDIM;  // [t][d]
    size_t baseV = (size_t)bh * HDIM * T_SEQ;  // [d][t]
    int row4 = tid >> 2, seg = tid & 3;

    int xt = 31 - blockIdx.y;
    int qb = xt * 64;
    int qrow = qb + wave * 16 + l16;

    const unsigned short* qr = Qp + baseQ + (size_t)qrow * HDIM;
    short8 qf0 = *(const short8*)(qr + quad * 8);
    short8 qf1 = *(const short8*)(qr + 32 + quad * 8);

    float4v o[4] = {};
    float lsum = 0.f;
    int nt = xt + 1;

    uint4 ka, kb2, va, vb;
    {
        const unsigned short* gk = Kp + baseQ + (size_t)row4 * HDIM + seg * 16;
        const unsigned short* gv = Vt + baseV + (size_t)row4 * T_SEQ + seg * 16;
        ka = *(const uint4*)gk; kb2 = *(const uint4*)(gk + 8);
        va = *(const uint4*)gv; vb = *(const uint4*)(gv + 8);
    }
    *(uint4*)(sK[0] + row4 * 72 + seg * 16) = ka;
    *(uint4*)(sK[0] + row4 * 72 + seg * 16 + 8) = kb2;
    *(uint4*)(sV[0] + row4 * 72 + seg * 16) = va;
    *(uint4*)(sV[0] + row4 * 72 + seg * 16 + 8) = vb;

    for (int t = 0; t < nt; t++) {
        int cur = t & 1;
        __syncthreads();
        if (t + 1 < nt) {
            const unsigned short* gk =
                Kp + baseQ + (size_t)((t + 1) * 64 + row4) * HDIM + seg * 16;
            const unsigned short* gv =
                Vt + baseV + (size_t)row4 * T_SEQ + (t + 1) * 64 + seg * 16;
            ka = *(const uint4*)gk; kb2 = *(const uint4*)(gk + 8);
            va = *(const uint4*)gv; vb = *(const uint4*)(gv + 8);
        }

        const unsigned short* cK = sK[cur];
        const unsigned short* cV = sV[cur];
        float4v s[4];
        for (int sub = 0; sub < 4; sub++) {
            short8 kf0 = *(const short8*)(cK + (sub * 16 + l16) * 72 + quad * 8);
            short8 kf1 =
                *(const short8*)(cK + (sub * 16 + l16) * 72 + 32 + quad * 8);
            float4v z = {};
            z = __builtin_amdgcn_mfma_f32_16x16x32_bf16(kf0, qf0, z, 0, 0, 0);
            z = __builtin_amdgcn_mfma_f32_16x16x32_bf16(kf1, qf1, z, 0, 0, 0);
            s[sub] = z;
        }

        bool need_mask = (t * 64 + 63) > (qb + wave * 16);  // wave-uniform
        float p[16];
        for (int sub = 0; sub < 4; sub++)
            for (int r = 0; r < 4; r++) {
                float v = s[sub][r];
                if (need_mask) {
                    int kg = t * 64 + sub * 16 + quad * 4 + r;
                    v = (kg <= qrow) ? v : -1e30f;
                }
                p[sub * 4 + r] = v;
            }
        unsigned ub[16];
        for (int i = 0; i < 16; i++) {
            float e = exp2f(p[i] - 16.0f);
            unsigned u = __builtin_bit_cast(unsigned, e) & 0xffff0000u;
            ub[i] = u;
            lsum += __builtin_bit_cast(float, u);
        }

        for (int sub = 0; sub < 4; sub++) {
            unsigned lo = __builtin_amdgcn_perm(ub[sub * 4 + 1], ub[sub * 4 + 0],
                                                0x07060302u);
            unsigned hi = __builtin_amdgcn_perm(ub[sub * 4 + 3], ub[sub * 4 + 2],
                                                0x07060302u);
            uint2 packed = {lo, hi};
            short4v pf = __builtin_bit_cast(short4v, packed);
            for (int dc = 0; dc < 4; dc++) {
                short4v vf = *(const short4v*)(
                    cV + (dc * 16 + l16) * 72 + sub * 16 + quad * 4);
                o[dc] = __builtin_amdgcn_mfma_f32_16x16x16bf16_1k(
                    vf, pf, o[dc], 0, 0, 0);
            }
        }

        if (t + 1 < nt) {
            int nxt = cur ^ 1;
            *(uint4*)(sK[nxt] + row4 * 72 + seg * 16) = ka;
            *(uint4*)(sK[nxt] + row4 * 72 + seg * 16 + 8) = kb2;
            *(uint4*)(sV[nxt] + row4 * 72 + seg * 16) = va;
            *(uint4*)(sV[nxt] + row4 * 72 + seg * 16 + 8) = vb;
        }
    }

    lsum += __shfl_xor(lsum, 16);
    lsum += __shfl_xor(lsum, 32);
    float inv = 1.0f / lsum;

    __syncthreads();
    for (int dc = 0; dc < 4; dc++) {
        short4v ov;
        for (int r = 0; r < 4; r++) ov[r] = (short)f2bf(o[dc][r] * inv);
        *(short4v*)(sK[0] + wave * 1152 + l16 * 72 + dc * 16 + quad * 4) = ov;
    }
    __syncthreads();
    int orow = lane >> 2, oseg = lane & 3;
    uint4 a = *(const uint4*)(sK[0] + wave * 1152 + orow * 72 + oseg * 16);
    uint4 b = *(const uint4*)(sK[0] + wave * 1152 + orow * 72 + oseg * 16 + 8);
    unsigned short* dst = att +
        (size_t)(bb * T_SEQ + qb + wave * 16 + orow) * CDIM + h * HDIM +
        oseg * 16;
    *(uint4*)dst = a;
    *(uint4*)(dst + 8) = b;
}

// ---------------- launch ----------------
extern "C" void kernel_launch(void* const* d_in, const int* in_sizes, int n_in,
                              void* d_out, int out_size, void* d_ws, size_t ws_size,
                              hipStream_t stream) {
    const float* x      = (const float*)d_in[0];   // [2,2048,1024]
    const float* W_attn = (const float*)d_in[1];   // [1024,3072]
    const float* W_proj = (const float*)d_in[2];   // [1024,1024]
    const float* b_proj = (const float*)d_in[3];   // [1024]
    float* out = (float*)d_out;                    // [2,2048,1024]

    unsigned short* xb   = (unsigned short*)d_ws;          // 4096*1024
    unsigned short* WaT  = xb  + 4096 * 1024;              // 3072*1024 (transposed)
    unsigned short* WpT  = WaT + 3072 * 1024;              // 1024*1024 (transposed)
    unsigned short* Karr = WpT + 1024 * 1024;              // [B,H,T,64]
    unsigned short* Qarr = Karr + 2 * 16 * 2048 * 64;      // [B,H,T,64] pre-scaled
    unsigned short* Varr = Qarr + 2 * 16 * 2048 * 64;      // [B,H,64,T] transposed
    unsigned short* attb = Varr + 2 * 16 * 2048 * 64;      // 4096*1024

    convert_f32_bf16_vec<<<4096, 256, 0, stream>>>(x, xb);
    transpose_f32_bf16<<<dim3(32, 96), 256, 0, stream>>>(W_attn, WaT, 1024, 3072);
    transpose_f32_bf16<<<dim3(32, 32), 256, 0, stream>>>(W_proj, WpT, 1024, 1024);
    gemm_qkv<<<dim3(24, 32), 256, 0, stream>>>(xb, WaT, Karr, Qarr, Varr);
    attn_fwd<<<dim3(32, 32), 256, 0, stream>>>(Qarr, Karr, Varr, attb);
    gemm_proj<<<dim3(16, 64), 256, 0, stream>>>(attb, WpT, b_proj, out);
}